// Round 9
// baseline (14422.328 us; speedup 1.0000x reference)
//
#include <hip/hip_runtime.h>
#include <stdint.h>

// ---------------------------------------------------------------------------
// ComplexApproximateBNN, round 12. R11 post-mortem: phase 16.5us = A-bypass
// 32MB (~9us) + two serialized syncs (~5us) + GEMM ~1us. R12 attacks both:
//  - n-tile 32->64 cols, K-split 8 (kq 0..7, kslice=512): per-block A reads
//    halve (64KB) -> device 16MB/phase. W-regs unchanged: 4 layers x
//    4 ntiles x 2 ksteps x bf16x8 = 128 VGPR, pinned per step.
//  - 64-col LDS reduce done in two 32-col passes reusing red[8][64][33].
//  - Grid barrier DELETED: single sync = combiner done-counter (32 RMWs/
//    phase), release fanned via per-group rel lines (R10 pattern). Partials
//    double-buffered on phase parity (skew <= 1 proven by counter chain).
//  - All coherence via proven primitives: RMW exchanges for cross-phase
//    writes, relaxed agent atomic loads for reads, zero fences.
// ---------------------------------------------------------------------------

typedef __bf16 bf16;
typedef __attribute__((ext_vector_type(8))) __bf16 bf16x8;
typedef __attribute__((ext_vector_type(4))) float f32x4;

#define BATCH 64
#define TSTEPS 128
#define INDIM 512
#define XDIM 2048
#define OUTDIM 256
#define SLOTE ((size_t)BATCH * XDIM)   // bf16 elems per [64][2048] slot
#define SLOTF ((size_t)BATCH * XDIM)   // f32 elems per partial slot
#define PBPAR (7 * SLOTF)              // one parity's partial region
#define NBLOCKS 256
#define GSTRIDE 64                     // u32 stride between counters = 256 B

__device__ __forceinline__ float apply_act(float h, int id) {
  switch (id) {
    case 0: return fmaxf(h, 0.0f);                       // relu
    case 1: return 1.0f / (1.0f + __expf(-h));           // sigmoid
    case 2: return tanhf(h);                             // tanh
    case 3: return h >= 0.0f ? h : 0.1f * h;             // leaky 0.1
    default: {                                           // selu
      const float sc = 1.0507009873554805f;
      const float al = 1.6732632423543772f;
      return h > 0.0f ? sc * h : sc * al * (__expf(h) - 1.0f);
    }
  }
}

// Agent-coherent 16B load as 2x8B relaxed atomic loads (proven R5/R9-R11).
__device__ __forceinline__ bf16x8 cload(const bf16* p) {
  union { unsigned long long q[2]; bf16x8 v; } u;
  const unsigned long long* qp = (const unsigned long long*)p;
  u.q[0] = __hip_atomic_load(qp, __ATOMIC_RELAXED, __HIP_MEMORY_SCOPE_AGENT);
  u.q[1] = __hip_atomic_load(qp + 1, __ATOMIC_RELAXED, __HIP_MEMORY_SCOPE_AGENT);
  return u.v;
}

// Coherent 8B store via atomic exchange (RMW at coherence point; proven R9).
__device__ __forceinline__ void cstore8(unsigned long long* p,
                                        unsigned long long v) {
  unsigned long long old = __hip_atomic_exchange(p, v, __ATOMIC_RELAXED,
                                                 __HIP_MEMORY_SCOPE_AGENT);
  asm volatile("" :: "v"(old));
}

__device__ __forceinline__ unsigned long long cload8(
    const unsigned long long* p) {
  return __hip_atomic_load(p, __ATOMIC_RELAXED, __HIP_MEMORY_SCOPE_AGENT);
}

// One layer phase, W-stationary, single-sync. Block (nt 0..31 = 64-col tile,
// kq 0..7 = 512-k slice; kq<4 -> A1, kq>=4 -> A2). Writers (kq!=0) publish
// f32 partials (parity-buffered) + per-nt flag. Combiner (kq==0) waits 7
// flags, combines lo + scale*hi + bias, act, ss, stores h, then bumps the
// global done-counter. Everyone then waits done >= 32*ph via grouped rel.
template <bool SCALE_A2, bool EMIT_SS, bool PLAIN_A1>
__device__ __forceinline__ void layer_phase(
    const int tid, const int nt, const int kq, const int bid,
    const bf16* __restrict__ A1, const bf16* __restrict__ A2,
    const bf16x8 (&wf)[4][2], const float* __restrict__ bias,
    const int* __restrict__ acts, const float* __restrict__ ss_in,
    float* __restrict__ ss_out, bf16* __restrict__ outb,
    float* __restrict__ pbuf, unsigned* __restrict__ flags,
    unsigned* __restrict__ bars, const unsigned ph,
    float (&red)[8][64][33]) {
  const int lane = tid & 63;
  const int w = tid >> 6;        // 0..7 : 64-k sub-slice within the 512
  const int l15 = lane & 15;
  const int kb8 = (lane >> 4) * 8;
  const int q4 = lane >> 4;

  const bf16* As = (kq >= 4) ? A2 : A1;
  const int koff = (kq & 3) * 512 + w * 64;
  const bf16* ap = As + (size_t)l15 * 2048 + koff + kb8;

  f32x4 acc[4][4];
  const f32x4 zero = {0.f, 0.f, 0.f, 0.f};
#pragma unroll
  for (int mt = 0; mt < 4; mt++)
#pragma unroll
    for (int ntl = 0; ntl < 4; ntl++) acc[mt][ntl] = zero;

  const bool plain = PLAIN_A1 && (kq < 4);
#pragma unroll
  for (int ks = 0; ks < 2; ks++) {
#pragma unroll
    for (int mt = 0; mt < 4; mt++) {
      const bf16* aptr = ap + (size_t)mt * 16 * 2048 + ks * 32;
      bf16x8 a = plain ? *(const bf16x8*)aptr : cload(aptr);
#pragma unroll
      for (int ntl = 0; ntl < 4; ntl++)
        acc[mt][ntl] = __builtin_amdgcn_mfma_f32_16x16x32_bf16(
            a, wf[ntl][ks], acc[mt][ntl], 0, 0, 0);
    }
  }

  // two-pass 8-wave reduction over 64 cols (reuses 32-col red buffer)
  const int row = tid >> 3;       // 0..63
  const int c4 = (tid & 7) * 4;   // 0..28
  float v[2][4];
#pragma unroll
  for (int h = 0; h < 2; h++) {
#pragma unroll
    for (int mt = 0; mt < 4; mt++)
#pragma unroll
      for (int j = 0; j < 2; j++)
#pragma unroll
        for (int r = 0; r < 4; r++)
          red[w][mt * 16 + q4 * 4 + r][j * 16 + l15] = acc[mt][2 * h + j][r];
    __syncthreads();
#pragma unroll
    for (int jj = 0; jj < 4; jj++) {
      float s = 0.f;
#pragma unroll
      for (int ww = 0; ww < 8; ww++) s += red[ww][row][c4 + jj];
      v[h][jj] = s;
    }
    __syncthreads();
  }

  const int cbase = nt * 64;
  unsigned* gbar = bars + (size_t)8 * GSTRIDE;

  if (kq != 0) {
    // writer: publish partial (parity-buffered), then per-nt flag
    float* pb = pbuf + (size_t)(ph & 1) * PBPAR + (size_t)(kq - 1) * SLOTF +
                (size_t)row * XDIM + cbase;
#pragma unroll
    for (int h = 0; h < 2; h++) {
      union { float f[2]; unsigned long long u; } pk;
      float* q = pb + h * 32 + c4;
      pk.f[0] = v[h][0]; pk.f[1] = v[h][1];
      cstore8((unsigned long long*)q, pk.u);
      pk.f[0] = v[h][2]; pk.f[1] = v[h][3];
      cstore8((unsigned long long*)(q + 2), pk.u);
    }
    __syncthreads();  // drain exchanges before flag
    if (tid == 0) {
      __hip_atomic_fetch_add(flags + (size_t)nt * GSTRIDE, 1u,
                             __ATOMIC_RELAXED, __HIP_MEMORY_SCOPE_AGENT);
    }
  } else {
    // combiner
    if (tid == 0) {
      while (__hip_atomic_load(flags + (size_t)nt * GSTRIDE, __ATOMIC_RELAXED,
                               __HIP_MEMORY_SCOPE_AGENT) < 7u * ph) {
        __builtin_amdgcn_s_sleep(2);
      }
    }
    __syncthreads();

    float lo[2][4], hi[2][4];
#pragma unroll
    for (int h = 0; h < 2; h++)
#pragma unroll
      for (int j = 0; j < 4; j++) {
        lo[h][j] = v[h][j];
        hi[h][j] = 0.f;
      }
    const float* pbase = pbuf + (size_t)(ph & 1) * PBPAR +
                         (size_t)row * XDIM + cbase;
#pragma unroll
    for (int kqi = 1; kqi < 8; kqi++) {
      const float* q = pbase + (size_t)(kqi - 1) * SLOTF;
#pragma unroll
      for (int h = 0; h < 2; h++) {
        union { unsigned long long u; float f[2]; } a, b;
        a.u = cload8((const unsigned long long*)(q + h * 32 + c4));
        b.u = cload8((const unsigned long long*)(q + h * 32 + c4 + 2));
        if (kqi < 4) {
          lo[h][0] += a.f[0]; lo[h][1] += a.f[1];
          lo[h][2] += b.f[0]; lo[h][3] += b.f[1];
        } else {
          hi[h][0] += a.f[0]; hi[h][1] += a.f[1];
          hi[h][2] += b.f[0]; hi[h][3] += b.f[1];
        }
      }
    }

    float scale = 1.0f;
    if (SCALE_A2) {
      float ssv = __hip_atomic_load(ss_in + row, __ATOMIC_RELAXED,
                                    __HIP_MEMORY_SCOPE_AGENT);
      scale = 1.0f / fmaxf(sqrtf(ssv), 1e-12f);
    }
    float ssl = 0.f;
#pragma unroll
    for (int h = 0; h < 2; h++) {
      union { bf16 b[4]; unsigned long long u; } hk;
#pragma unroll
      for (int j = 0; j < 4; j++) {
        int c = cbase + h * 32 + c4 + j;
        float pre = lo[h][j] + (SCALE_A2 ? scale * hi[h][j] : hi[h][j]) +
                    bias[c];
        float av = apply_act(pre, acts[c]);
        hk.b[j] = (bf16)av;
        ssl += av * av;
      }
      cstore8((unsigned long long*)(outb + (size_t)row * XDIM + cbase +
                                    h * 32 + c4),
              hk.u);
    }
    if (EMIT_SS) {
      ssl += __shfl_xor(ssl, 1);
      ssl += __shfl_xor(ssl, 2);
      ssl += __shfl_xor(ssl, 4);
      if ((tid & 7) == 0) atomicAdd(ss_out + row, ssl);
    }
    __syncthreads();  // drain h exchanges + ss before done-tick
    if (tid == 0) {
      __hip_atomic_fetch_add(gbar, 1u, __ATOMIC_RELAXED,
                             __HIP_MEMORY_SCOPE_AGENT);
    }
  }

  // single phase wait: done-counter fanned out via per-group rel lines
  if (tid == 0) {
    unsigned* rel = bars + (size_t)(9 + (bid >> 5)) * GSTRIDE;
    if ((bid & 31) == 0) {
      while (__hip_atomic_load(gbar, __ATOMIC_RELAXED,
                               __HIP_MEMORY_SCOPE_AGENT) < 32u * ph) {
        __builtin_amdgcn_s_sleep(4);
      }
      __hip_atomic_fetch_add(rel, 1u, __ATOMIC_RELAXED,
                             __HIP_MEMORY_SCOPE_AGENT);
    } else {
      while (__hip_atomic_load(rel, __ATOMIC_RELAXED,
                               __HIP_MEMORY_SCOPE_AGENT) < ph) {
        __builtin_amdgcn_s_sleep(4);
      }
    }
  }
  __syncthreads();
}

struct StepParams {
  bf16* h0;           // [128][64][2048], slices also reused as h4 slots 2..
  bf16* extra;        // h4 slots 0,1
  bf16* h1;
  bf16* h2a;
  bf16* h2b;
  bf16* h3;
  const bf16* whb;    // [4][2048][4096]
  const float* b_h;   // [4][2048]
  const int* acts;    // [5][2048]
  float* ss_li;       // [(T+1)*64]
  float* ss_bp;       // [(T+1)*64]
  float* pbuf;        // [2 parity][7][64][2048] f32 partials
  unsigned* flags;    // per-nt combine flags (GSTRIDE-padded)
  unsigned* bar;      // done-counter + rel lines (zeroed)
};

__global__ __launch_bounds__(512, 2) void step_loop(StepParams p) {
  __shared__ float red[8][64][33];
  const int tid = threadIdx.x;
  const int bid = blockIdx.x;
  const int nt = bid & 31;    // 64-col n-tile
  const int kq = bid >> 5;    // 512-k slice (0..3: A1, 4..7: A2)
  const int lane = tid & 63;
  const int w = tid >> 6;
  const int l15 = lane & 15;
  const int kb8 = (lane >> 4) * 8;
  const size_t wstr = (size_t)XDIM * 2 * XDIM;

  // One-time W preload: 4 layers x 4 ntiles x 2 ksteps x bf16x8 = 128 VGPR.
  const bf16* wb = p.whb + (size_t)(nt * 64 + l15) * 4096 + kq * 512 +
                   w * 64 + kb8;
  bf16x8 wf0[4][2], wf1[4][2], wf2[4][2], wf3[4][2];
#pragma unroll
  for (int ntl = 0; ntl < 4; ntl++) {
#pragma unroll
    for (int ks = 0; ks < 2; ks++) {
      const bf16* q = wb + (size_t)ntl * 16 * 4096 + ks * 32;
      wf0[ntl][ks] = *(const bf16x8*)q;
      wf1[ntl][ks] = *(const bf16x8*)(q + wstr);
      wf2[ntl][ks] = *(const bf16x8*)(q + 2 * wstr);
      wf3[ntl][ks] = *(const bf16x8*)(q + 3 * wstr);
    }
  }

  unsigned ph = 0;
  for (int t = 0; t < TSTEPS; t++) {
    // Pin W fragments: opaque asm keeps them register-resident across phases.
#pragma unroll
    for (int ntl = 0; ntl < 4; ntl++)
#pragma unroll
      for (int ks = 0; ks < 2; ks++) {
        asm volatile("" : "+v"(wf0[ntl][ks]), "+v"(wf1[ntl][ks]),
                          "+v"(wf2[ntl][ks]), "+v"(wf3[ntl][ks]));
      }

    const bf16* h4t = (t < 2) ? p.extra + (size_t)t * SLOTE
                              : p.h0 + (size_t)(t - 2) * SLOTE;
    bf16* h4n = (t + 1 < 2) ? p.extra + (size_t)(t + 1) * SLOTE
                            : p.h0 + (size_t)(t - 1) * SLOTE;
    bf16* h2n = (t & 1) ? p.h2b : p.h2a;
    const bf16* h2o = (t & 1) ? p.h2a : p.h2b;

    // h1 = act([h0_t, norm(h4_t)] @ W0^T + b0)   (h0 pristine -> plain)
    ++ph;
    layer_phase<true, false, true>(tid, nt, kq, bid,
                                   p.h0 + (size_t)t * SLOTE, h4t, wf0, p.b_h,
                                   p.acts + XDIM, p.ss_bp + t * BATCH,
                                   nullptr, p.h1, p.pbuf, p.flags, p.bar, ph,
                                   red);

    // h2 = act([h1, norm(h2_old)] @ W1^T + b1); emit ss_li[t+1]
    ++ph;
    layer_phase<true, true, false>(tid, nt, kq, bid, p.h1, h2o, wf1,
                                   p.b_h + XDIM, p.acts + 2 * XDIM,
                                   p.ss_li + t * BATCH,
                                   p.ss_li + (t + 1) * BATCH, h2n, p.pbuf,
                                   p.flags, p.bar, ph, red);

    // h3 = act([h2, h1] @ W2^T + b2)
    ++ph;
    layer_phase<false, false, false>(tid, nt, kq, bid, h2n, p.h1, wf2,
                                     p.b_h + 2 * XDIM, p.acts + 3 * XDIM,
                                     nullptr, nullptr, p.h3, p.pbuf, p.flags,
                                     p.bar, ph, red);

    // h4 = act([h3, h2] @ W3^T + b3) -> slot t+1; emit ss_bp[t+1]
    ++ph;
    layer_phase<false, true, false>(tid, nt, kq, bid, p.h3, h2n, wf3,
                                    p.b_h + 3 * XDIM, p.acts + 4 * XDIM,
                                    nullptr, p.ss_bp + (t + 1) * BATCH, h4n,
                                    p.pbuf, p.flags, p.bar, ph, red);
  }
}

// h0 precompute: [8192,512]@[512->2048], rows r=b*128+t remapped to [t][b][n]
__global__ __launch_bounds__(256) void h0_gemm(
    const bf16* __restrict__ A, const bf16* __restrict__ W,
    const float* __restrict__ bias, const int* __restrict__ acts,
    bf16* __restrict__ outp) {
  const int tid = threadIdx.x;
  const int lane = tid & 63;
  const int wv = tid >> 6;
  const int wm = (wv & 1) * 32;
  const int wn = (wv >> 1) * 64;
  const int nblk = blockIdx.x * 128;
  const int mblk = blockIdx.y * 64;
  const int l15 = lane & 15;
  const int kb8 = (lane >> 4) * 8;

  f32x4 acc[2][4];
  const f32x4 zero = {0.f, 0.f, 0.f, 0.f};
#pragma unroll
  for (int i = 0; i < 2; i++)
#pragma unroll
    for (int j = 0; j < 4; j++) acc[i][j] = zero;

  for (int kt = 0; kt < INDIM; kt += 32) {
    bf16x8 a[2], b[4];
#pragma unroll
    for (int mt = 0; mt < 2; mt++) {
      int m = mblk + wm + mt * 16 + l15;
      a[mt] = *(const bf16x8*)(A + (size_t)m * INDIM + kt + kb8);
    }
#pragma unroll
    for (int nt = 0; nt < 4; nt++) {
      int n = nblk + wn + nt * 16 + l15;
      b[nt] = *(const bf16x8*)(W + (size_t)n * INDIM + kt + kb8);
    }
#pragma unroll
    for (int mt = 0; mt < 2; mt++)
#pragma unroll
      for (int nt = 0; nt < 4; nt++)
        acc[mt][nt] = __builtin_amdgcn_mfma_f32_16x16x32_bf16(a[mt], b[nt], acc[mt][nt], 0, 0, 0);
  }

#pragma unroll
  for (int mt = 0; mt < 2; mt++) {
#pragma unroll
    for (int nt = 0; nt < 4; nt++) {
      int n = nblk + wn + nt * 16 + l15;
      float bv = bias[n];
      int aid = acts[n];
#pragma unroll
      for (int rr = 0; rr < 4; rr++) {
        int m = wm + mt * 16 + (lane >> 4) * 4 + rr;
        float v = apply_act(acc[mt][nt][rr] + bv, aid);
        int rowg = mblk + m;  // = b*128 + t
        int bb = rowg >> 7;
        int tt = rowg & 127;
        outp[((size_t)tt * BATCH + bb) * XDIM + n] = (bf16)v;
      }
    }
  }
}

// batched output layer: for each t, y_t = act(h4slot(t+1) @ Wout^T + bout).
__global__ __launch_bounds__(256) void ybat_gemm(
    const bf16* __restrict__ extra, const bf16* __restrict__ h0,
    const bf16* __restrict__ Wout, const float* __restrict__ bout,
    const int* __restrict__ oact, float* __restrict__ out) {
  const int t = blockIdx.y;
  const int s = t + 1;
  const bf16* A = (s < 2) ? (extra + (size_t)s * SLOTE)
                          : (h0 + (size_t)(s - 2) * SLOTE);
  const int tid = threadIdx.x;
  const int lane = tid & 63;
  const int wv = tid >> 6;
  const int wm = (wv & 1) * 32;
  const int wn = (wv >> 1) * 64;
  const int nblk = blockIdx.x * 128;
  const int l15 = lane & 15;
  const int kb8 = (lane >> 4) * 8;

  f32x4 acc[2][4];
  const f32x4 zero = {0.f, 0.f, 0.f, 0.f};
#pragma unroll
  for (int i = 0; i < 2; i++)
#pragma unroll
    for (int j = 0; j < 4; j++) acc[i][j] = zero;

  for (int kt = 0; kt < XDIM; kt += 32) {
    bf16x8 a[2], b[4];
#pragma unroll
    for (int mt = 0; mt < 2; mt++) {
      int m = wm + mt * 16 + l15;
      a[mt] = *(const bf16x8*)(A + (size_t)m * XDIM + kt + kb8);
    }
#pragma unroll
    for (int nt = 0; nt < 4; nt++) {
      int n = nblk + wn + nt * 16 + l15;
      b[nt] = *(const bf16x8*)(Wout + (size_t)n * XDIM + kt + kb8);
    }
#pragma unroll
    for (int mt = 0; mt < 2; mt++)
#pragma unroll
      for (int nt = 0; nt < 4; nt++)
        acc[mt][nt] = __builtin_amdgcn_mfma_f32_16x16x32_bf16(a[mt], b[nt], acc[mt][nt], 0, 0, 0);
  }

#pragma unroll
  for (int mt = 0; mt < 2; mt++) {
#pragma unroll
    for (int nt = 0; nt < 4; nt++) {
      int n = nblk + wn + nt * 16 + l15;
      float bv = bout[n];
      int aid = oact[n];
#pragma unroll
      for (int rr = 0; rr < 4; rr++) {
        int b = wm + mt * 16 + (lane >> 4) * 4 + rr;  // batch row
        float v = apply_act(acc[mt][nt][rr] + bv, aid);
        out[((size_t)b * TSTEPS + t) * OUTDIM + n] = v;
      }
    }
  }
}

__global__ __launch_bounds__(256) void cvt_bf16(
    const float* __restrict__ in, bf16* __restrict__ out, int n4) {
  int i = blockIdx.x * 256 + threadIdx.x;
  if (i < n4) {
    float4 v = ((const float4*)in)[i];
    union { bf16 b[4]; unsigned long long u; } pk;
    pk.b[0] = (bf16)v.x;
    pk.b[1] = (bf16)v.y;
    pk.b[2] = (bf16)v.z;
    pk.b[3] = (bf16)v.w;
    ((unsigned long long*)out)[i] = pk.u;
  }
}

__global__ __launch_bounds__(256) void zero32(uint32_t* __restrict__ p, int n) {
  int i = blockIdx.x * 256 + threadIdx.x;
  if (i < n) p[i] = 0u;
}

extern "C" void kernel_launch(void* const* d_in, const int* in_sizes, int n_in,
                              void* d_out, int out_size, void* d_ws, size_t ws_size,
                              hipStream_t stream) {
  const float* x     = (const float*)d_in[0];   // [64,128,512]
  const float* W_in  = (const float*)d_in[1];   // [2048,512]
  const float* b_in  = (const float*)d_in[2];   // [2048]
  const float* W_h   = (const float*)d_in[3];   // [4,2048,4096]
  const float* b_h   = (const float*)d_in[4];   // [4,2048]
  const float* W_out = (const float*)d_in[5];   // [256,2048]
  const float* b_out = (const float*)d_in[6];   // [256]
  const int* act_ids = (const int*)d_in[7];     // [5,2048]
  const int* out_act = (const int*)d_in[8];     // [256]
  float* out = (float*)d_out;                   // [64,128,256]

  char* w = (char*)d_ws;
  bf16* xbf   = (bf16*)w; w += (size_t)BATCH * TSTEPS * INDIM * 2;   // 8 MB
  bf16* winb  = (bf16*)w; w += (size_t)XDIM * INDIM * 2;             // 2 MB
  bf16* whb   = (bf16*)w; w += (size_t)4 * XDIM * (2 * XDIM) * 2;    // 64 MB
  bf16* woutb = (bf16*)w; w += (size_t)OUTDIM * XDIM * 2;            // 1 MB
  bf16* h0    = (bf16*)w; w += (size_t)TSTEPS * SLOTE * 2;           // 32 MB (doubles as h4 slots 2..)
  bf16* h1    = (bf16*)w; w += SLOTE * 2;
  bf16* h3    = (bf16*)w; w += SLOTE * 2;
  float* pbuf = (float*)w; w += (size_t)2 * PBPAR * 4;               // 7.3 MB partials
  // ---- zero region ----
  char* zstart = w;
  bf16* extra = (bf16*)w; w += 2 * SLOTE * 2;   // h4 slots 0,1 (slot 0 must be 0)
  bf16* h2a   = (bf16*)w; w += SLOTE * 2;
  bf16* h2b   = (bf16*)w; w += SLOTE * 2;
  float* ss_li = (float*)w; w += (size_t)(TSTEPS + 1) * BATCH * 4;
  float* ss_bp = (float*)w; w += (size_t)(TSTEPS + 1) * BATCH * 4;
  unsigned* flags = (unsigned*)w; w += (size_t)64 * GSTRIDE * 4;  // combine flags
  unsigned* bar = (unsigned*)w; w += (size_t)32 * GSTRIDE * 4;    // done + rel
  int zero_u32 = (int)((w - zstart) / 4);

  cvt_bf16<<<4096, 256, 0, stream>>>(x, xbf, (BATCH * TSTEPS * INDIM) / 4);
  cvt_bf16<<<1024, 256, 0, stream>>>(W_in, winb, (XDIM * INDIM) / 4);
  cvt_bf16<<<32768, 256, 0, stream>>>(W_h, whb, (4 * XDIM * 2 * XDIM) / 4);
  cvt_bf16<<<512, 256, 0, stream>>>(W_out, woutb, (OUTDIM * XDIM) / 4);
  zero32<<<(zero_u32 + 255) / 256, 256, 0, stream>>>((uint32_t*)zstart, zero_u32);
  h0_gemm<<<dim3(16, 128), 256, 0, stream>>>(xbf, winb, b_in, act_ids, h0);

  StepParams sp;
  sp.h0 = h0;
  sp.extra = extra;
  sp.h1 = h1;
  sp.h2a = h2a;
  sp.h2b = h2b;
  sp.h3 = h3;
  sp.whb = whb;
  sp.b_h = b_h;
  sp.acts = act_ids;
  sp.ss_li = ss_li;
  sp.ss_bp = ss_bp;
  sp.pbuf = pbuf;
  sp.flags = flags;
  sp.bar = bar;
  void* kp[] = {&sp};
  (void)hipLaunchCooperativeKernel((const void*)step_loop, dim3(NBLOCKS),
                                   dim3(512), kp, 0, stream);

  // all y_t in one GEMM over the stored h4 slots
  ybat_gemm<<<dim3(2, TSTEPS), 256, 0, stream>>>(
      extra, h0, woutb, b_out, out_act, out);
}

// Round 10
// 8597.288 us; speedup vs baseline: 1.6775x; 1.6775x over previous
//
#include <hip/hip_runtime.h>
#include <stdint.h>

// ---------------------------------------------------------------------------
// ComplexApproximateBNN, round 13. R12 bundled 3 changes and regressed
// (partial volume 2.3x, LDS conflicts 2x). R13 = exact R11 (best, 8846us)
// + ONE change: the post-combine grid barrier is replaced by a combiner-
// done counter. Chain per phase: writers publish partials (u64 exchanges) +
// per-nt flag; combiner waits 3 flags, combines, acts, stores h (exchanges),
// __syncthreads (drains returning RMWs), ticks done; 8 group leaders poll
// done>=64*ph and tick padded rel lines; all blocks poll their rel.
// Saves the 256-arrival barrier tree (~2us of serialized MALL RTTs).
// Partials parity-double-buffered so no WAR without the barrier.
// All coherence primitives unchanged (proven R9-R11): RMW writes,
// relaxed agent atomic loads, zero fences -> W stays in regs/L2.
// ---------------------------------------------------------------------------

typedef __bf16 bf16;
typedef __attribute__((ext_vector_type(8))) __bf16 bf16x8;
typedef __attribute__((ext_vector_type(4))) float f32x4;

#define BATCH 64
#define TSTEPS 128
#define INDIM 512
#define XDIM 2048
#define OUTDIM 256
#define SLOTE ((size_t)BATCH * XDIM)  // elements per [b][2048] slot
#define NBLOCKS 256
#define GSTRIDE 64                    // u32 stride between counters = 256 B
#define PBPAR ((size_t)3 * BATCH * XDIM)  // one parity's partial region (f32)

__device__ __forceinline__ float apply_act(float h, int id) {
  switch (id) {
    case 0: return fmaxf(h, 0.0f);                       // relu
    case 1: return 1.0f / (1.0f + __expf(-h));           // sigmoid
    case 2: return tanhf(h);                             // tanh
    case 3: return h >= 0.0f ? h : 0.1f * h;             // leaky 0.1
    default: {                                           // selu
      const float sc = 1.0507009873554805f;
      const float al = 1.6732632423543772f;
      return h > 0.0f ? sc * h : sc * al * (__expf(h) - 1.0f);
    }
  }
}

// Agent-coherent 16B load as 2x8B relaxed atomic loads (proven R5/R9-R11).
__device__ __forceinline__ bf16x8 cload(const bf16* p) {
  union { unsigned long long q[2]; bf16x8 v; } u;
  const unsigned long long* qp = (const unsigned long long*)p;
  u.q[0] = __hip_atomic_load(qp, __ATOMIC_RELAXED, __HIP_MEMORY_SCOPE_AGENT);
  u.q[1] = __hip_atomic_load(qp + 1, __ATOMIC_RELAXED, __HIP_MEMORY_SCOPE_AGENT);
  return u.v;
}

// Coherent 8B store via atomic exchange (RMW at coherence point; proven R9).
// Old value consumed by empty asm so the xchg can't demote to a store; the
// returned value also makes vmcnt track RMW completion (drained by barrier).
__device__ __forceinline__ void cstore8(unsigned long long* p,
                                        unsigned long long v) {
  unsigned long long old = __hip_atomic_exchange(p, v, __ATOMIC_RELAXED,
                                                 __HIP_MEMORY_SCOPE_AGENT);
  asm volatile("" :: "v"(old));
}

__device__ __forceinline__ unsigned long long cload8(
    const unsigned long long* p) {
  return __hip_atomic_load(p, __ATOMIC_RELAXED, __HIP_MEMORY_SCOPE_AGENT);
}

// Phase-completion wait (replaces grid barrier): done is ticked once per
// phase by each of the 64 combiners; 8 group leaders fan it out to padded
// rel lines (R10's storm-free pattern).
__device__ __forceinline__ void phase_wait(unsigned* bars, int bid,
                                           unsigned ph) {
  if (threadIdx.x == 0) {
    unsigned* done = bars + (size_t)8 * GSTRIDE;
    unsigned* rel = bars + (size_t)(9 + (bid >> 5)) * GSTRIDE;
    if ((bid & 31) == 0) {
      while (__hip_atomic_load(done, __ATOMIC_RELAXED,
                               __HIP_MEMORY_SCOPE_AGENT) < 64u * ph) {
        __builtin_amdgcn_s_sleep(2);
      }
      __hip_atomic_fetch_add(rel, 1u, __ATOMIC_RELAXED,
                             __HIP_MEMORY_SCOPE_AGENT);
    } else {
      while (__hip_atomic_load(rel, __ATOMIC_RELAXED,
                               __HIP_MEMORY_SCOPE_AGENT) < ph) {
        __builtin_amdgcn_s_sleep(2);
      }
    }
  }
  __syncthreads();
}

// One layer phase, W-stationary (R11 body). Block (nt = 32-col tile, kq =
// K-quarter). kq>=1: publish partial (parity-buffered u64 exchanges) + flag.
// kq=0: wait 3 flags, read partials, combine lo + scale*hi + bias, act, ss,
// store h, tick done.
template <bool SCALE_A2, bool EMIT_SS, bool PLAIN_A1>
__device__ __forceinline__ void layer_phase(
    const int tid, const int nt, const int kq,
    const bf16* __restrict__ A1, const bf16* __restrict__ A2,
    const bf16x8 (&wf)[2][4], const float* __restrict__ bias,
    const int* __restrict__ acts, const float* __restrict__ ss_in,
    float* __restrict__ ss_out, bf16* __restrict__ outb,
    float* __restrict__ pbuf, unsigned* __restrict__ flags,
    unsigned* __restrict__ bars, const unsigned ph,
    float (&red)[8][64][33]) {
  const int lane = tid & 63;
  const int w = tid >> 6;        // 0..7 : 128-k slice within the K-quarter
  const int l15 = lane & 15;
  const int kb8 = (lane >> 4) * 8;
  const int q4 = lane >> 4;

  const bf16* As = (kq >= 2) ? A2 : A1;
  const int koff = (kq & 1) * 1024 + w * 128;
  const bf16* ap = As + (size_t)l15 * 2048 + koff + kb8;

  f32x4 acc[4][2];
  const f32x4 zero = {0.f, 0.f, 0.f, 0.f};
#pragma unroll
  for (int mt = 0; mt < 4; mt++) {
    acc[mt][0] = zero;
    acc[mt][1] = zero;
  }

  const bool plain = PLAIN_A1 && (kq < 2);
#pragma unroll
  for (int ks = 0; ks < 4; ks++) {
#pragma unroll
    for (int mt = 0; mt < 4; mt++) {
      const bf16* aptr = ap + (size_t)mt * 16 * 2048 + ks * 32;
      bf16x8 a = plain ? *(const bf16x8*)aptr : cload(aptr);
      acc[mt][0] = __builtin_amdgcn_mfma_f32_16x16x32_bf16(a, wf[0][ks], acc[mt][0], 0, 0, 0);
      acc[mt][1] = __builtin_amdgcn_mfma_f32_16x16x32_bf16(a, wf[1][ks], acc[mt][1], 0, 0, 0);
    }
  }

#pragma unroll
  for (int mt = 0; mt < 4; mt++)
#pragma unroll
    for (int n2 = 0; n2 < 2; n2++)
#pragma unroll
      for (int r = 0; r < 4; r++)
        red[w][mt * 16 + q4 * 4 + r][n2 * 16 + l15] = acc[mt][n2][r];
  __syncthreads();

  // per-thread ownership: row = tid>>3 (0..63), cols c4..c4+3
  const int row = tid >> 3;
  const int c4 = (tid & 7) * 4;
  float v[4];
#pragma unroll
  for (int j = 0; j < 4; j++) {
    float s = 0.f;
#pragma unroll
    for (int ww = 0; ww < 8; ww++) s += red[ww][row][c4 + j];
    v[j] = s;
  }

  float* pbase = pbuf + (size_t)(ph & 1) * PBPAR;
  const size_t pidx = ((size_t)row) * XDIM + nt * 32 + c4;
  if (kq != 0) {
    // writer: publish partial for this K-quarter (parity-buffered)
    float* pb = pbase + (size_t)(kq - 1) * BATCH * XDIM + pidx;
    union { float f[2]; unsigned long long u; } pk;
    pk.f[0] = v[0]; pk.f[1] = v[1];
    cstore8((unsigned long long*)pb, pk.u);
    pk.f[0] = v[2]; pk.f[1] = v[3];
    cstore8((unsigned long long*)(pb + 2), pk.u);
    __syncthreads();  // drain exchanges (vmcnt 0) before flag
    if (tid == 0) {
      __hip_atomic_fetch_add(flags + (size_t)nt * GSTRIDE, 1u,
                             __ATOMIC_RELAXED, __HIP_MEMORY_SCOPE_AGENT);
    }
  } else {
    // combiner
    if (tid == 0) {
      while (__hip_atomic_load(flags + (size_t)nt * GSTRIDE, __ATOMIC_RELAXED,
                               __HIP_MEMORY_SCOPE_AGENT) < 3u * ph) {
        __builtin_amdgcn_s_sleep(1);
      }
    }
    __syncthreads();
    float p1[4], p2[4], p3[4];
#pragma unroll
    for (int h = 0; h < 2; h++) {
      union { unsigned long long u; float f[2]; } u1, u2, u3;
      const unsigned long long* b1 =
          (const unsigned long long*)(pbase + pidx) + h;
      u1.u = cload8(b1);
      u2.u = cload8(b1 + (size_t)BATCH * XDIM / 2);
      u3.u = cload8(b1 + (size_t)BATCH * XDIM);
      p1[h * 2] = u1.f[0]; p1[h * 2 + 1] = u1.f[1];
      p2[h * 2] = u2.f[0]; p2[h * 2 + 1] = u2.f[1];
      p3[h * 2] = u3.f[0]; p3[h * 2 + 1] = u3.f[1];
    }
    float scale = 1.0f;
    if (SCALE_A2) {
      float ssv = __hip_atomic_load(ss_in + row, __ATOMIC_RELAXED,
                                    __HIP_MEMORY_SCOPE_AGENT);
      scale = 1.0f / fmaxf(sqrtf(ssv), 1e-12f);
    }
    const int cg = nt * 32 + c4;
    union { bf16 b[4]; unsigned long long u; } hk;
    float ssl = 0.f;
#pragma unroll
    for (int j = 0; j < 4; j++) {
      float lo = v[j] + p1[j];
      float hi = p2[j] + p3[j];
      float pre = (SCALE_A2 ? (lo + scale * hi) : (lo + hi)) + bias[cg + j];
      float av = apply_act(pre, acts[cg + j]);
      hk.b[j] = (bf16)av;
      ssl += av * av;
    }
    if (EMIT_SS) {
      ssl += __shfl_xor(ssl, 1);
      ssl += __shfl_xor(ssl, 2);
      ssl += __shfl_xor(ssl, 4);
      if ((tid & 7) == 0) atomicAdd(ss_out + row, ssl);
    }
    cstore8((unsigned long long*)(outb + (size_t)row * XDIM + cg), hk.u);
    __syncthreads();  // drain h exchanges + ss atomics before done-tick
    if (tid == 0) {
      __hip_atomic_fetch_add(bars + (size_t)8 * GSTRIDE, 1u, __ATOMIC_RELAXED,
                             __HIP_MEMORY_SCOPE_AGENT);
    }
  }
}

struct StepParams {
  bf16* h0;           // [128][64][2048], slices also reused as h4 slots 2..
  bf16* extra;        // h4 slots 0,1
  bf16* h1;
  bf16* h2a;
  bf16* h2b;
  bf16* h3;
  const bf16* whb;    // [4][2048][4096]
  const float* b_h;   // [4][2048]
  const int* acts;    // [5][2048]
  float* ss_li;       // [(T+1)*64]
  float* ss_bp;       // [(T+1)*64]
  float* pbuf;        // [2 parity][3][64][2048] f32 K-quarter partials
  unsigned* flags;    // [64*GSTRIDE] combine flags
  unsigned* bar;      // done counter + rel lines (zeroed), 32*GSTRIDE u32s
};

__global__ __launch_bounds__(512, 2) void step_loop(StepParams p) {
  __shared__ float red[8][64][33];
  const int tid = threadIdx.x;
  const int bid = blockIdx.x;
  const int nt = bid & 63;    // 32-col n-tile
  const int kq = bid >> 6;    // K-quarter (0,1: A1 halves; 2,3: A2 halves)
  const int lane = tid & 63;
  const int w = tid >> 6;
  const int l15 = lane & 15;
  const int kb8 = (lane >> 4) * 8;
  const size_t wstr = (size_t)XDIM * 2 * XDIM;

  // One-time W preload: 4 layers x 2 ntiles x 4 ksteps x bf16x8 = 128 VGPR.
  const bf16* wb = p.whb + (size_t)(nt * 32 + l15) * 4096 + kq * 1024 +
                   w * 128 + kb8;
  bf16x8 wf0[2][4], wf1[2][4], wf2[2][4], wf3[2][4];
#pragma unroll
  for (int n2 = 0; n2 < 2; n2++) {
#pragma unroll
    for (int ks = 0; ks < 4; ks++) {
      const bf16* q = wb + (size_t)n2 * 16 * 4096 + ks * 32;
      wf0[n2][ks] = *(const bf16x8*)q;
      wf1[n2][ks] = *(const bf16x8*)(q + wstr);
      wf2[n2][ks] = *(const bf16x8*)(q + 2 * wstr);
      wf3[n2][ks] = *(const bf16x8*)(q + 3 * wstr);
    }
  }

  unsigned ph = 0;
  for (int t = 0; t < TSTEPS; t++) {
    // Pin W fragments: opaque asm touch defeats rematerialization/reload.
#pragma unroll
    for (int n2 = 0; n2 < 2; n2++)
#pragma unroll
      for (int ks = 0; ks < 4; ks++) {
        asm volatile("" : "+v"(wf0[n2][ks]), "+v"(wf1[n2][ks]),
                          "+v"(wf2[n2][ks]), "+v"(wf3[n2][ks]));
      }

    const bf16* h4t = (t < 2) ? p.extra + (size_t)t * SLOTE
                              : p.h0 + (size_t)(t - 2) * SLOTE;
    bf16* h4n = (t + 1 < 2) ? p.extra + (size_t)(t + 1) * SLOTE
                            : p.h0 + (size_t)(t - 1) * SLOTE;
    bf16* h2n = (t & 1) ? p.h2b : p.h2a;
    const bf16* h2o = (t & 1) ? p.h2a : p.h2b;

    // h1 = act([h0_t, norm(h4_t)] @ W0^T + b0)   (h0 pristine -> plain)
    ++ph;
    layer_phase<true, false, true>(tid, nt, kq, p.h0 + (size_t)t * SLOTE, h4t,
                                   wf0, p.b_h, p.acts + XDIM,
                                   p.ss_bp + t * BATCH, nullptr, p.h1,
                                   p.pbuf, p.flags, p.bar, ph, red);
    phase_wait(p.bar, bid, ph);

    // h2 = act([h1, norm(h2_old)] @ W1^T + b1); emit ss_li[t+1]
    ++ph;
    layer_phase<true, true, false>(tid, nt, kq, p.h1, h2o, wf1, p.b_h + XDIM,
                                   p.acts + 2 * XDIM, p.ss_li + t * BATCH,
                                   p.ss_li + (t + 1) * BATCH, h2n,
                                   p.pbuf, p.flags, p.bar, ph, red);
    phase_wait(p.bar, bid, ph);

    // h3 = act([h2, h1] @ W2^T + b2)
    ++ph;
    layer_phase<false, false, false>(tid, nt, kq, h2n, p.h1, wf2,
                                     p.b_h + 2 * XDIM, p.acts + 3 * XDIM,
                                     nullptr, nullptr, p.h3,
                                     p.pbuf, p.flags, p.bar, ph, red);
    phase_wait(p.bar, bid, ph);

    // h4 = act([h3, h2] @ W3^T + b3) -> slot t+1; emit ss_bp[t+1]
    ++ph;
    layer_phase<false, true, false>(tid, nt, kq, p.h3, h2n, wf3,
                                    p.b_h + 3 * XDIM, p.acts + 4 * XDIM,
                                    nullptr, p.ss_bp + (t + 1) * BATCH, h4n,
                                    p.pbuf, p.flags, p.bar, ph, red);
    phase_wait(p.bar, bid, ph);
  }
}

// h0 precompute: [8192,512]@[512->2048], rows r=b*128+t remapped to [t][b][n]
__global__ __launch_bounds__(256) void h0_gemm(
    const bf16* __restrict__ A, const bf16* __restrict__ W,
    const float* __restrict__ bias, const int* __restrict__ acts,
    bf16* __restrict__ outp) {
  const int tid = threadIdx.x;
  const int lane = tid & 63;
  const int wv = tid >> 6;
  const int wm = (wv & 1) * 32;
  const int wn = (wv >> 1) * 64;
  const int nblk = blockIdx.x * 128;
  const int mblk = blockIdx.y * 64;
  const int l15 = lane & 15;
  const int kb8 = (lane >> 4) * 8;

  f32x4 acc[2][4];
  const f32x4 zero = {0.f, 0.f, 0.f, 0.f};
#pragma unroll
  for (int i = 0; i < 2; i++)
#pragma unroll
    for (int j = 0; j < 4; j++) acc[i][j] = zero;

  for (int kt = 0; kt < INDIM; kt += 32) {
    bf16x8 a[2], b[4];
#pragma unroll
    for (int mt = 0; mt < 2; mt++) {
      int m = mblk + wm + mt * 16 + l15;
      a[mt] = *(const bf16x8*)(A + (size_t)m * INDIM + kt + kb8);
    }
#pragma unroll
    for (int nt = 0; nt < 4; nt++) {
      int n = nblk + wn + nt * 16 + l15;
      b[nt] = *(const bf16x8*)(W + (size_t)n * INDIM + kt + kb8);
    }
#pragma unroll
    for (int mt = 0; mt < 2; mt++)
#pragma unroll
      for (int nt = 0; nt < 4; nt++)
        acc[mt][nt] = __builtin_amdgcn_mfma_f32_16x16x32_bf16(a[mt], b[nt], acc[mt][nt], 0, 0, 0);
  }

#pragma unroll
  for (int mt = 0; mt < 2; mt++) {
#pragma unroll
    for (int nt = 0; nt < 4; nt++) {
      int n = nblk + wn + nt * 16 + l15;
      float bv = bias[n];
      int aid = acts[n];
#pragma unroll
      for (int rr = 0; rr < 4; rr++) {
        int m = wm + mt * 16 + (lane >> 4) * 4 + rr;
        float v = apply_act(acc[mt][nt][rr] + bv, aid);
        int rowg = mblk + m;  // = b*128 + t
        int bb = rowg >> 7;
        int tt = rowg & 127;
        outp[((size_t)tt * BATCH + bb) * XDIM + n] = (bf16)v;
      }
    }
  }
}

// batched output layer: for each t, y_t = act(h4slot(t+1) @ Wout^T + bout).
__global__ __launch_bounds__(256) void ybat_gemm(
    const bf16* __restrict__ extra, const bf16* __restrict__ h0,
    const bf16* __restrict__ Wout, const float* __restrict__ bout,
    const int* __restrict__ oact, float* __restrict__ out) {
  const int t = blockIdx.y;
  const int s = t + 1;
  const bf16* A = (s < 2) ? (extra + (size_t)s * SLOTE)
                          : (h0 + (size_t)(s - 2) * SLOTE);
  const int tid = threadIdx.x;
  const int lane = tid & 63;
  const int wv = tid >> 6;
  const int wm = (wv & 1) * 32;
  const int wn = (wv >> 1) * 64;
  const int nblk = blockIdx.x * 128;
  const int l15 = lane & 15;
  const int kb8 = (lane >> 4) * 8;

  f32x4 acc[2][4];
  const f32x4 zero = {0.f, 0.f, 0.f, 0.f};
#pragma unroll
  for (int i = 0; i < 2; i++)
#pragma unroll
    for (int j = 0; j < 4; j++) acc[i][j] = zero;

  for (int kt = 0; kt < XDIM; kt += 32) {
    bf16x8 a[2], b[4];
#pragma unroll
    for (int mt = 0; mt < 2; mt++) {
      int m = wm + mt * 16 + l15;
      a[mt] = *(const bf16x8*)(A + (size_t)m * XDIM + kt + kb8);
    }
#pragma unroll
    for (int nt = 0; nt < 4; nt++) {
      int n = nblk + wn + nt * 16 + l15;
      b[nt] = *(const bf16x8*)(Wout + (size_t)n * XDIM + kt + kb8);
    }
#pragma unroll
    for (int mt = 0; mt < 2; mt++)
#pragma unroll
      for (int nt = 0; nt < 4; nt++)
        acc[mt][nt] = __builtin_amdgcn_mfma_f32_16x16x32_bf16(a[mt], b[nt], acc[mt][nt], 0, 0, 0);
  }

#pragma unroll
  for (int mt = 0; mt < 2; mt++) {
#pragma unroll
    for (int nt = 0; nt < 4; nt++) {
      int n = nblk + wn + nt * 16 + l15;
      float bv = bout[n];
      int aid = oact[n];
#pragma unroll
      for (int rr = 0; rr < 4; rr++) {
        int b = wm + mt * 16 + (lane >> 4) * 4 + rr;  // batch row
        float v = apply_act(acc[mt][nt][rr] + bv, aid);
        out[((size_t)b * TSTEPS + t) * OUTDIM + n] = v;
      }
    }
  }
}

__global__ __launch_bounds__(256) void cvt_bf16(
    const float* __restrict__ in, bf16* __restrict__ out, int n4) {
  int i = blockIdx.x * 256 + threadIdx.x;
  if (i < n4) {
    float4 v = ((const float4*)in)[i];
    union { bf16 b[4]; unsigned long long u; } pk;
    pk.b[0] = (bf16)v.x;
    pk.b[1] = (bf16)v.y;
    pk.b[2] = (bf16)v.z;
    pk.b[3] = (bf16)v.w;
    ((unsigned long long*)out)[i] = pk.u;
  }
}

__global__ __launch_bounds__(256) void zero32(uint32_t* __restrict__ p, int n) {
  int i = blockIdx.x * 256 + threadIdx.x;
  if (i < n) p[i] = 0u;
}

extern "C" void kernel_launch(void* const* d_in, const int* in_sizes, int n_in,
                              void* d_out, int out_size, void* d_ws, size_t ws_size,
                              hipStream_t stream) {
  const float* x     = (const float*)d_in[0];   // [64,128,512]
  const float* W_in  = (const float*)d_in[1];   // [2048,512]
  const float* b_in  = (const float*)d_in[2];   // [2048]
  const float* W_h   = (const float*)d_in[3];   // [4,2048,4096]
  const float* b_h   = (const float*)d_in[4];   // [4,2048]
  const float* W_out = (const float*)d_in[5];   // [256,2048]
  const float* b_out = (const float*)d_in[6];   // [256]
  const int* act_ids = (const int*)d_in[7];     // [5,2048]
  const int* out_act = (const int*)d_in[8];     // [256]
  float* out = (float*)d_out;                   // [64,128,256]

  char* w = (char*)d_ws;
  bf16* xbf   = (bf16*)w; w += (size_t)BATCH * TSTEPS * INDIM * 2;   // 8 MB
  bf16* winb  = (bf16*)w; w += (size_t)XDIM * INDIM * 2;             // 2 MB
  bf16* whb   = (bf16*)w; w += (size_t)4 * XDIM * (2 * XDIM) * 2;    // 64 MB
  bf16* woutb = (bf16*)w; w += (size_t)OUTDIM * XDIM * 2;            // 1 MB
  bf16* h0    = (bf16*)w; w += (size_t)TSTEPS * SLOTE * 2;           // 32 MB (doubles as h4 slots 2..)
  bf16* h1    = (bf16*)w; w += SLOTE * 2;
  bf16* h3    = (bf16*)w; w += SLOTE * 2;
  float* pbuf = (float*)w; w += (size_t)2 * PBPAR * 4;               // 3 MB partials
  // ---- zero region ----
  char* zstart = w;
  bf16* extra = (bf16*)w; w += 2 * SLOTE * 2;   // h4 slots 0,1 (slot 0 must be 0)
  bf16* h2a   = (bf16*)w; w += SLOTE * 2;
  bf16* h2b   = (bf16*)w; w += SLOTE * 2;
  float* ss_li = (float*)w; w += (size_t)(TSTEPS + 1) * BATCH * 4;
  float* ss_bp = (float*)w; w += (size_t)(TSTEPS + 1) * BATCH * 4;
  unsigned* flags = (unsigned*)w; w += (size_t)64 * GSTRIDE * 4;  // combine flags
  unsigned* bar = (unsigned*)w; w += (size_t)32 * GSTRIDE * 4;    // done + rel
  int zero_u32 = (int)((w - zstart) / 4);

  cvt_bf16<<<4096, 256, 0, stream>>>(x, xbf, (BATCH * TSTEPS * INDIM) / 4);
  cvt_bf16<<<1024, 256, 0, stream>>>(W_in, winb, (XDIM * INDIM) / 4);
  cvt_bf16<<<32768, 256, 0, stream>>>(W_h, whb, (4 * XDIM * 2 * XDIM) / 4);
  cvt_bf16<<<512, 256, 0, stream>>>(W_out, woutb, (OUTDIM * XDIM) / 4);
  zero32<<<(zero_u32 + 255) / 256, 256, 0, stream>>>((uint32_t*)zstart, zero_u32);
  h0_gemm<<<dim3(16, 128), 256, 0, stream>>>(xbf, winb, b_in, act_ids, h0);

  StepParams sp;
  sp.h0 = h0;
  sp.extra = extra;
  sp.h1 = h1;
  sp.h2a = h2a;
  sp.h2b = h2b;
  sp.h3 = h3;
  sp.whb = whb;
  sp.b_h = b_h;
  sp.acts = act_ids;
  sp.ss_li = ss_li;
  sp.ss_bp = ss_bp;
  sp.pbuf = pbuf;
  sp.flags = flags;
  sp.bar = bar;
  void* kp[] = {&sp};
  (void)hipLaunchCooperativeKernel((const void*)step_loop, dim3(NBLOCKS),
                                   dim3(512), kp, 0, stream);

  // all y_t in one GEMM over the stored h4 slots
  ybat_gemm<<<dim3(2, TSTEPS), 256, 0, stream>>>(
      extra, h0, woutb, b_out, out_act, out);
}